// Round 3
// baseline (1060.688 us; speedup 1.0000x reference)
//
#include <hip/hip_runtime.h>

// NearestNbrNegSampler: B=2048, D=256
// n[i][j][k] = y[i][k] + (j==k ? 1 : 0) - (j-D==k ? 1 : 0),  j in [0,2D)
// nmsk[i][j] = all_k( l[i][k] <= n[i][j][k] <= u[i][k] )
// d_out = n (B*2D*D f32) then nmsk (B*2D f32 0/1), concatenated flat.
//
// Write-bound: 1.078 GB stores. Harness fill proves 6.2 TB/s on this buffer
// at ~10% occupancy with long sequential streams. So: one wave == one i-tile
// (512 KB), streamed fully contiguously (1 KB/store, monotonic addresses).
// No LDS, no barriers: mask fail-count via wave shuffle reduction.

#define BB 2048
#define DD 256

typedef float v4f __attribute__((ext_vector_type(4)));

__global__ __launch_bounds__(256) void nnns_kernel(
    const float* __restrict__ l,
    const float* __restrict__ u,
    const float* __restrict__ y,
    float* __restrict__ n_out,
    float* __restrict__ m_out)
{
    const int lane = threadIdx.x & 63;
    const int w    = threadIdx.x >> 6;
    const int i    = blockIdx.x * 4 + w;   // one tile per wave
    const int kb   = lane * 4;

    const v4f y4 = *(const v4f*)(y + i * DD + kb);
    const v4f l4 = *(const v4f*)(l + i * DD + kb);
    const v4f u4 = *(const v4f*)(u + i * DD + kb);

    // ---- mask: per-component unperturbed in-bounds, wave-summed fail count
    const int c0 = (l4.x <= y4.x) && (y4.x <= u4.x);
    const int c1 = (l4.y <= y4.y) && (y4.y <= u4.y);
    const int c2 = (l4.z <= y4.z) && (y4.z <= u4.z);
    const int c3 = (l4.w <= y4.w) && (y4.w <= u4.w);
    int f = 4 - (c0 + c1 + c2 + c3);
    #pragma unroll
    for (int off = 32; off; off >>= 1) f += __shfl_xor(f, off);

    // row j passes iff (no fails among k!=j) && (perturbed value in bounds)
    // no fails among k!=j  <=>  f==0 || (f==1 && y[j] itself was the fail)
    const float mp0 = ((f == 0) || (f == 1 && !c0)) && (l4.x <= y4.x + 1.0f) && (y4.x + 1.0f <= u4.x);
    const float mp1 = ((f == 0) || (f == 1 && !c1)) && (l4.y <= y4.y + 1.0f) && (y4.y + 1.0f <= u4.y);
    const float mp2 = ((f == 0) || (f == 1 && !c2)) && (l4.z <= y4.z + 1.0f) && (y4.z + 1.0f <= u4.z);
    const float mp3 = ((f == 0) || (f == 1 && !c3)) && (l4.w <= y4.w + 1.0f) && (y4.w + 1.0f <= u4.w);
    const float mm0 = ((f == 0) || (f == 1 && !c0)) && (l4.x <= y4.x - 1.0f) && (y4.x - 1.0f <= u4.x);
    const float mm1 = ((f == 0) || (f == 1 && !c1)) && (l4.y <= y4.y - 1.0f) && (y4.y - 1.0f <= u4.y);
    const float mm2 = ((f == 0) || (f == 1 && !c2)) && (l4.z <= y4.z - 1.0f) && (y4.z - 1.0f <= u4.z);
    const float mm3 = ((f == 0) || (f == 1 && !c3)) && (l4.w <= y4.w - 1.0f) && (y4.w - 1.0f <= u4.w);
    v4f mp = {mp0, mp1, mp2, mp3};
    v4f mm = {mm0, mm1, mm2, mm3};
    *(v4f*)(m_out + (size_t)i * (2 * DD) + kb)      = mp;
    *(v4f*)(m_out + (size_t)i * (2 * DD) + DD + kb) = mm;

    // ---- n: stream this wave's 512-row tile fully sequentially.
    // row j: modified k0 = j&255 -> lane k0>>2, component j&3, sign +/- by j<256.
    v4f* p = (v4f*)(n_out + (size_t)i * (2 * DD) * DD) + lane;  // row stride = 64 v4f

    #pragma unroll 4
    for (int t4 = 0; t4 < DD; t4 += 4) {          // rows j = t4..t4+3 (+1 branch)
        const int tl = t4 >> 2;
        v4f v;
        v = y4; v.x += (lane == tl) ? 1.0f : 0.0f; __builtin_nontemporal_store(v, p); p += 64;
        v = y4; v.y += (lane == tl) ? 1.0f : 0.0f; __builtin_nontemporal_store(v, p); p += 64;
        v = y4; v.z += (lane == tl) ? 1.0f : 0.0f; __builtin_nontemporal_store(v, p); p += 64;
        v = y4; v.w += (lane == tl) ? 1.0f : 0.0f; __builtin_nontemporal_store(v, p); p += 64;
    }
    #pragma unroll 4
    for (int t4 = 0; t4 < DD; t4 += 4) {          // rows j = 256+t4.. (-1 branch)
        const int tl = t4 >> 2;
        v4f v;
        v = y4; v.x -= (lane == tl) ? 1.0f : 0.0f; __builtin_nontemporal_store(v, p); p += 64;
        v = y4; v.y -= (lane == tl) ? 1.0f : 0.0f; __builtin_nontemporal_store(v, p); p += 64;
        v = y4; v.z -= (lane == tl) ? 1.0f : 0.0f; __builtin_nontemporal_store(v, p); p += 64;
        v = y4; v.w -= (lane == tl) ? 1.0f : 0.0f; __builtin_nontemporal_store(v, p); p += 64;
    }
}

extern "C" void kernel_launch(void* const* d_in, const int* in_sizes, int n_in,
                              void* d_out, int out_size, void* d_ws, size_t ws_size,
                              hipStream_t stream) {
    // setup_inputs order: a(0), b(1), c(2), l(3), u(4), h(5), y(6)
    const float* l = (const float*)d_in[3];
    const float* u = (const float*)d_in[4];
    const float* y = (const float*)d_in[6];

    float* n_out = (float*)d_out;                                // B*2D*D
    float* m_out = (float*)d_out + (size_t)BB * (2 * DD) * DD;   // B*2D

    nnns_kernel<<<dim3(BB / 4), dim3(256), 0, stream>>>(l, u, y, n_out, m_out);
}